// Round 9
// baseline (26314.722 us; speedup 1.0000x reference)
//
#include <hip/hip_runtime.h>
#include <stdint.h>

#define V 4096
#define D 128
#define E 12288
#define NPAD 16384
#define HALF 8192
#define TARGET 2048
#define MAXM (V - TARGET)    // 2048 kept merges
#define LCAP 192             // list capacity (u16 entries)
#define MAXW 1024            // winner cap per round
#define ACAP 4096            // total accept cap (forest bound < V)

// ws layout (bytes)
#define WS_BM     0u                               // V*V bits = 2 MB dedupe bitmap
#define WS_LISTS  (V * (V / 8u))                   // V*LCAP*2 = 1.5 MB
#define WS_LEN    (WS_LISTS + V * LCAP * 2u)       // V u32
#define WS_PRI    (WS_LEN + V * 4u)                // V float
#define WS_KEYS   (WS_PRI + V * 4u)                // NPAD u64
#define WS_PK     (WS_KEYS + NPAD * 8u)            // E u32 (sorted packed edges)
#define WS_PAIRS  (WS_PK + E * 4u)                 // MAXM u32
#define WS_MCOUNT (WS_PAIRS + MAXM * 4u)           // 1 int
#define WS_ALIVE  (WS_MCOUNT + 16u)                // V u8

__device__ __forceinline__ unsigned getf(const uint4& r, int c) {
    unsigned lo = (c & 2) ? r.z : r.x;
    unsigned hi = (c & 2) ? r.w : r.y;
    return (c & 1) ? hi : lo;
}

// chunked membership scan: is id present among first n entries of list p?
__device__ __forceinline__ bool inlist(const unsigned short* p, int n, int id) {
    const uint4* pv = (const uint4*)p;
    for (int i0 = 0; i0 < n; i0 += 8) {
        uint4 c = pv[i0 >> 3];
#pragma unroll
        for (int t = 0; t < 4; t++) {
            unsigned wv = getf(c, t);
            int n0 = i0 + 2 * t;
            if (n0 < n && (int)((wv & 0xFFFFu) >> 2) == id) return true;
            if (n0 + 1 < n && (int)(wv >> 18) == id) return true;
        }
    }
    return false;
}

// build adjacency lists; bitmap dedupes duplicate input edges (ref .set is idempotent)
__global__ void k_build(const int* __restrict__ edges, unsigned* __restrict__ bm,
                        unsigned* __restrict__ lenG, unsigned short* __restrict__ lists) {
    int e = blockIdx.x * 256 + threadIdx.x;
    if (e < E) {
        int a = edges[e], b = edges[E + e];
        unsigned o1 = atomicOr(&bm[(a << 7) + (b >> 5)], 1u << (b & 31));
        if (!((o1 >> (b & 31)) & 1u)) {
            unsigned ia = atomicAdd(&lenG[a], 1u);
            if (ia < LCAP) lists[a * LCAP + ia] = (unsigned short)((b << 2) | 2);
        }
        unsigned o2 = atomicOr(&bm[(b << 7) + (a >> 5)], 1u << (a & 31));
        if (!((o2 >> (a & 31)) & 1u)) {
            unsigned ib = atomicAdd(&lenG[b], 1u);
            if (ib < LCAP) lists[b * LCAP + ib] = (unsigned short)((a << 2) | 2);
        }
    }
}

// numpy pairwise f32 sum for n=128 (matches np oracle reduction order)
__global__ void k_pri(const float* __restrict__ f, float* __restrict__ pri) {
    int v = blockIdx.x * 256 + threadIdx.x;
    if (v < V) {
        const float* p = f + v * D;
        float r[8];
#pragma unroll
        for (int j = 0; j < 8; j++) r[j] = __fmul_rn(p[j], p[j]);
        for (int i = 8; i < D; i += 8) {
#pragma unroll
            for (int j = 0; j < 8; j++)
                r[j] = __fadd_rn(r[j], __fmul_rn(p[i + j], p[i + j]));
        }
        float s01 = __fadd_rn(r[0], r[1]);
        float s23 = __fadd_rn(r[2], r[3]);
        float s45 = __fadd_rn(r[4], r[5]);
        float s67 = __fadd_rn(r[6], r[7]);
        pri[v] = __fadd_rn(__fadd_rn(s01, s23), __fadd_rn(s45, s67));
    }
}

__global__ void k_keys(const int* __restrict__ edges, const float* __restrict__ pri,
                       unsigned long long* __restrict__ keys) {
    int s = blockIdx.x * 256 + threadIdx.x;
    if (s < NPAD) {
        unsigned long long rec;
        if (s < E) {
            int a = edges[s], b = edges[E + s];
            float k = __fadd_rn(pri[a], pri[b]);   // epri >= 0 -> bits monotone
            rec = ((unsigned long long)__float_as_uint(k) << 32) | (unsigned)s;
        } else {
            rec = (0xFFFFFFFFull << 32) | (unsigned)s;
        }
        keys[s] = rec;
    }
}

__launch_bounds__(1024)
__global__ void k_sort2(unsigned long long* __restrict__ keys) {
    __shared__ unsigned long long srt[HALF];
    const int tid = threadIdx.x;
    unsigned long long* base = keys + blockIdx.x * HALF;
    for (int s = tid; s < HALF; s += 1024) srt[s] = base[s];
    __syncthreads();
    for (int k = 2; k <= HALF; k <<= 1) {
        for (int j = k >> 1; j >= 1; j >>= 1) {
            for (int i = tid; i < HALF; i += 1024) {
                int ixj = i ^ j;
                if (ixj > i) {
                    unsigned long long x = srt[i], y = srt[ixj];
                    bool up = ((i & k) == 0);
                    if ((x > y) == up) { srt[i] = y; srt[ixj] = x; }
                }
            }
            __syncthreads();
        }
    }
    for (int s = tid; s < HALF; s += 1024) base[s] = srt[s];
}

__launch_bounds__(64)
__global__ void k_mergepath(const unsigned long long* __restrict__ keys,
                            const int* __restrict__ edges, unsigned* __restrict__ pkG) {
    int t = blockIdx.x * 64 + threadIdx.x;
    if (t >= E / 64) return;
    const unsigned long long* A = keys;
    const unsigned long long* B = keys + HALF;
    int d = t * 64;
    int lo = d > HALF ? d - HALF : 0;
    int hi = d < HALF ? d : HALF;
    while (lo < hi) {
        int mid = (lo + hi) >> 1;
        if (A[mid] < B[d - 1 - mid]) lo = mid + 1; else hi = mid;
    }
    int ia = lo, ib = d - lo;
    for (int o = d; o < d + 64; o++) {
        bool takeA = (ib >= HALF) || (ia < HALF && A[ia] < B[ib]);
        unsigned long long r = takeA ? A[ia++] : B[ib++];
        int e = (int)(r & 0xFFFFFFFFull);
        int a = edges[e], b = edges[E + e];
        pkG[o] = ((unsigned)a << 16) | (unsigned)b;
    }
}

// 1024 threads, ONE block: local-min parallel greedy (exact), unbounded run,
// then sort accepts by order and keep the first 2048.
__launch_bounds__(1024, 1)
__global__ void k_collapse(const unsigned* __restrict__ pkG, const unsigned* __restrict__ lenG,
                           unsigned short* lists, unsigned* __restrict__ pairsG,
                           int* __restrict__ mcountG, uint8_t* __restrict__ aliveG,
                           float* __restrict__ out) {
    __shared__ unsigned minE[V];              // 16 KB  per-vertex min flagged order
    __shared__ unsigned short markM[V];       // 8 KB   winner mark: (order<<1)|isV1
    __shared__ uint8_t  alv[V];               // 4 KB
    __shared__ unsigned short len_[V];        // 8 KB
    __shared__ uint8_t  status[E];            // 12 KB  0=undec 1=rej 2=acc
    __shared__ unsigned short wOrd[MAXW];     // 2 KB
    __shared__ unsigned short rAcc[MAXW];     // 2 KB  this-round accepts (order)
    __shared__ unsigned short rL1[MAXW];      // 2 KB  saved len(v1)
    __shared__ unsigned short accOrd[ACAP];   // 8 KB  all accepts (orders)
    __shared__ int nw, naccR, mcnt, flagCnt;
    const int tid = threadIdx.x;

    for (int v = tid; v < V; v += 1024) {
        unsigned l = lenG[v];
        len_[v] = (unsigned short)(l > LCAP ? LCAP : l);
        alv[v] = 1; minE[v] = 0xFFFFFFFFu; markM[v] = 0xFFFF;
    }
    for (int e = tid; e < E; e += 1024) status[e] = 0;
    if (tid == 0) mcnt = 0;
    __syncthreads();

    for (int round = 0; round < 512; round++) {
        if (tid == 0) { nw = 0; naccR = 0; flagCnt = 0; }
        __syncthreads();

        // PASS1: evaluate predicate (monotone -> reject is final); flagged do minE
        for (int e = tid; e < E; e += 1024) {
            if (status[e]) continue;
            unsigned pk = pkG[e];
            int a = (int)(pk >> 16), b = (int)(pk & 0xFFFFu);
            if (!alv[a] || !alv[b]) { status[e] = 1; continue; }
            unsigned val = 0; bool found = false;
            int la = len_[a];
            const uint4* pl = (const uint4*)(lists + (size_t)a * LCAP);
            for (int i0 = 0; i0 < la && !found; i0 += 8) {
                uint4 c = pl[i0 >> 3];
#pragma unroll
                for (int t2 = 0; t2 < 4; t2++) {
                    unsigned wv = getf(c, t2);
                    int n0 = i0 + 2 * t2;
                    if (n0 < la && (int)((wv & 0xFFFFu) >> 2) == b) { val = wv & 3u; found = true; }
                    if (n0 + 1 < la && (int)(wv >> 18) == b) { val = (wv >> 16) & 3u; found = true; }
                }
            }
            if (!found || val != 2u) { status[e] = 1; continue; }
            flagCnt = 1;
            atomicMin(&minE[a], (unsigned)e);
            atomicMin(&minE[b], (unsigned)e);
        }
        __syncthreads();
        if (flagCnt == 0) break;

        // PASS2: winners = min flagged order at BOTH endpoints; post marks
        for (int e = tid; e < E; e += 1024) {
            if (status[e]) continue;
            unsigned pk = pkG[e];
            int a = (int)(pk >> 16), b = (int)(pk & 0xFFFFu);
            if (minE[a] == (unsigned)e && minE[b] == (unsigned)e) {
                int t = atomicAdd(&nw, 1);
                if (t < MAXW) {
                    wOrd[t] = (unsigned short)e;
                    markM[a] = (unsigned short)(e << 1);          // v0 mark
                    markM[b] = (unsigned short)((e << 1) | 1);    // v1 mark
                }
            }
        }
        __syncthreads();
        int nww = nw < MAXW ? nw : MAXW;

        // PASS3: adjacency demotion (lower order survives) + accept + task A (rebuild v0)
        for (int t = tid; t < nww; t += 1024) {
            int e = wOrd[t];
            unsigned pk = pkG[e];
            int a = (int)(pk >> 16), b = (int)(pk & 0xFFFFu);
            unsigned short* pa = lists + (size_t)a * LCAP;
            unsigned short* pb = lists + (size_t)b * LCAP;
            int la = len_[a], lb = len_[b];
            bool dem = false;
            {   // v1-side: any lower-order winner endpoint in N(b) -> demote
                const uint4* pv = (const uint4*)pb;
                for (int i0 = 0; i0 < lb && !dem; i0 += 8) {
                    uint4 c = pv[i0 >> 3];
#pragma unroll
                    for (int t2 = 0; t2 < 4; t2++) {
                        unsigned wv = getf(c, t2);
                        int n0 = i0 + 2 * t2;
                        int id0 = (int)((wv & 0xFFFFu) >> 2), id1 = (int)(wv >> 18);
                        if (n0 < lb && id0 < V) {
                            unsigned m = markM[id0];
                            if (m != 0xFFFFu && (int)(m >> 1) < e) dem = true;
                        }
                        if (n0 + 1 < lb && id1 < V) {
                            unsigned m = markM[id1];
                            if (m != 0xFFFFu && (int)(m >> 1) < e) dem = true;
                        }
                    }
                }
            }
            {   // v0-side: lower-order winner's DYING endpoint in N(a) -> demote
                const uint4* pv = (const uint4*)pa;
                for (int i0 = 0; i0 < la && !dem; i0 += 8) {
                    uint4 c = pv[i0 >> 3];
#pragma unroll
                    for (int t2 = 0; t2 < 4; t2++) {
                        unsigned wv = getf(c, t2);
                        int n0 = i0 + 2 * t2;
                        int id0 = (int)((wv & 0xFFFFu) >> 2), id1 = (int)(wv >> 18);
                        if (n0 < la && id0 < V) {
                            unsigned m = markM[id0];
                            if (m != 0xFFFFu && (m & 1u) && (int)(m >> 1) < e) dem = true;
                        }
                        if (n0 + 1 < la && id1 < V) {
                            unsigned m = markM[id1];
                            if (m != 0xFFFFu && (m & 1u) && (int)(m >> 1) < e) dem = true;
                        }
                    }
                }
            }
            if (dem) continue;                          // stays undecided; retries
            // ACCEPT (predicate final: all earlier incident edges decided)
            status[e] = 2;
            int r = atomicAdd(&naccR, 1);
            rAcc[r] = (unsigned short)e;
            rL1[r] = (unsigned short)lb;
            int ai = atomicAdd(&mcnt, 1);
            if (ai < ACAP) accOrd[ai] = (unsigned short)e;
            // TASK A: rebuild v0's list compacted (in place; only this thread touches it)
            int wn = 0;
            for (int i = 0; i < la; i++) {
                unsigned short tv = pa[i];
                int id = tv >> 2;
                if (id >= V || id == b) continue;
                bool inb = inlist(pb, lb, id);          // shared neighbor -> clamp 3
                pa[wn++] = inb ? (unsigned short)((id << 2) | 3u) : tv;
            }
            int wn0 = wn;
            for (int j = 0; j < lb; j++) {
                unsigned short uv = pb[j];
                int id = uv >> 2;
                if (id >= V || id == a) continue;
                if (!inlist(pa, wn0, id) && wn < LCAP) pa[wn++] = uv;  // new neighbor
            }
            len_[a] = (unsigned short)wn;
            len_[b] = 0;
            alv[b] = 0;
        }
        __syncthreads();

        // PASS4: task B — fix lists of x in N(v1): 8 threads per accepted merge
        int na = naccR;
        for (int s = tid; s < na * 8; s += 1024) {
            int t = s >> 3, j0 = s & 7;
            int e = rAcc[t];
            unsigned pk = pkG[e];
            int a = (int)(pk >> 16), b = (int)(pk & 0xFFFFu);
            int l1 = rL1[t];
            const unsigned short* pb = lists + (size_t)b * LCAP;
            for (int j = j0; j < l1; j += 8) {
                unsigned short uv = pb[j];
                int x = uv >> 2;
                if (x >= V || x == a) continue;
                unsigned short* px = lists + (size_t)x * LCAP;
                int lx = len_[x];
                int pV1 = -1, pV0 = -1;
                const uint4* pv = (const uint4*)px;
                for (int i0 = 0; i0 < lx; i0 += 8) {
                    uint4 c = pv[i0 >> 3];
#pragma unroll
                    for (int t2 = 0; t2 < 4; t2++) {
                        unsigned wv = getf(c, t2);
                        int n0 = i0 + 2 * t2;
                        int id0 = (int)((wv & 0xFFFFu) >> 2), id1 = (int)(wv >> 18);
                        if (n0 < lx) { if (id0 == b) pV1 = n0; else if (id0 == a) pV0 = n0; }
                        if (n0 + 1 < lx) { if (id1 == b) pV1 = n0 + 1; else if (id1 == a) pV0 = n0 + 1; }
                    }
                }
                if (pV1 < 0) continue;
                if (pV0 >= 0) {                          // x adj both: clamp a-entry, kill b-entry
                    px[pV0] = (unsigned short)((a << 2) | 3u);
                    px[pV1] = 0xFFFF;
                } else {                                 // rewrite b-entry -> (a, val)
                    px[pV1] = (unsigned short)((a << 2) | (uv & 3u));
                }
            }
        }
        __syncthreads();

        // PASS5: reset minE/marks at endpoints of undecided edges and all winners
        for (int e = tid; e < E; e += 1024) {
            if (status[e]) continue;
            unsigned pk = pkG[e];
            int a = (int)(pk >> 16), b = (int)(pk & 0xFFFFu);
            minE[a] = 0xFFFFFFFFu; minE[b] = 0xFFFFFFFFu;
            markM[a] = 0xFFFF; markM[b] = 0xFFFF;
        }
        for (int t = tid; t < nww; t += 1024) {
            int e = wOrd[t];
            unsigned pk = pkG[e];
            int a = (int)(pk >> 16), b = (int)(pk & 0xFFFFu);
            minE[a] = 0xFFFFFFFFu; minE[b] = 0xFFFFFFFFu;
            markM[a] = 0xFFFF; markM[b] = 0xFFFF;
        }
        __syncthreads();
    }

    // FINAL: sort accepts by order, keep first K=min(M,2048); rebuild alive
    int M = mcnt; if (M > ACAP) M = ACAP;
    for (int i = tid; i < ACAP; i += 1024) if (i >= M) accOrd[i] = 0xFFFF;
    __syncthreads();
    for (int k = 2; k <= ACAP; k <<= 1) {
        for (int j = k >> 1; j >= 1; j >>= 1) {
            for (int i = tid; i < ACAP; i += 1024) {
                int ix = i ^ j;
                if (ix > i) {
                    unsigned short x = accOrd[i], y = accOrd[ix];
                    bool up = ((i & k) == 0);
                    if ((x > y) == up) { accOrd[i] = y; accOrd[ix] = x; }
                }
            }
            __syncthreads();
        }
    }
    int K = M < MAXM ? M : MAXM;
    for (int v = tid; v < V; v += 1024) alv[v] = 1;
    __syncthreads();
    for (int i = tid; i < K; i += 1024) {
        int e = accOrd[i];
        unsigned pk = pkG[e];
        pairsG[i] = pk;                                  // ascending order for k_apply
        alv[pk & 0xFFFFu] = 0;
    }
    __syncthreads();
    for (int v = tid; v < V; v += 1024) {
        aliveG[v] = alv[v];
        out[V * D + v] = alv[v] ? 1.0f : 0.0f;
    }
    if (tid == 0) { mcountG[0] = K; out[V * D + V] = (float)(V - K); }
}

// Replay merge forest: per-vertex (root, weight) then scatter-add w*f[v] into out[root].
__launch_bounds__(256)
__global__ void k_apply(const float* __restrict__ f, const unsigned* __restrict__ pairsG,
                        const int* __restrict__ mcountG, float* __restrict__ out) {
    __shared__ unsigned pl[MAXM];
    __shared__ int rootL[256];
    __shared__ float wL[256];
    const int tid = threadIdx.x;
    const int mc = mcountG[0];
    for (int j = tid; j < mc; j += 256) pl[j] = pairsG[j];
    __syncthreads();
    int cur = blockIdx.x * 256 + tid;
    float w = 1.0f;
    for (int j = 0; j < mc; j++) {
        unsigned p = pl[j];
        int v0 = (int)(p >> 16), v1 = (int)(p & 0xFFFFu);
        if (cur == v1) { cur = v0; w *= 0.5f; }
        else if (cur == v0) w *= 0.5f;
    }
    rootL[tid] = cur;
    wL[tid] = w;
    __syncthreads();
    const int sub = tid >> 7;
    const int d = tid & 127;
    for (int s = 0; s < 256; s += 2) {
        int idx = s + sub;
        int vv = blockIdx.x * 256 + idx;
        atomicAdd(&out[rootL[idx] * D + d], wL[idx] * f[vv * D + d]);
    }
}

extern "C" void kernel_launch(void* const* d_in, const int* in_sizes, int n_in,
                              void* d_out, int out_size, void* d_ws, size_t ws_size,
                              hipStream_t stream) {
    (void)in_sizes; (void)n_in; (void)out_size; (void)ws_size;
    const float* features = (const float*)d_in[0];
    const int* edges = (const int*)d_in[1];
    uint8_t* ws = (uint8_t*)d_ws;
    unsigned* bm = (unsigned*)(ws + WS_BM);
    unsigned short* lists = (unsigned short*)(ws + WS_LISTS);
    unsigned* lenG = (unsigned*)(ws + WS_LEN);
    float* pri = (float*)(ws + WS_PRI);
    unsigned long long* keys = (unsigned long long*)(ws + WS_KEYS);
    unsigned* pkG = (unsigned*)(ws + WS_PK);
    unsigned* pairsG = (unsigned*)(ws + WS_PAIRS);
    int* mcountG = (int*)(ws + WS_MCOUNT);
    uint8_t* aliveG = ws + WS_ALIVE;
    float* out = (float*)d_out;

    hipMemsetAsync(bm, 0, (size_t)V * (V / 8), stream);
    hipMemsetAsync(lenG, 0, (size_t)V * 4, stream);
    hipMemsetAsync(out, 0, (size_t)V * D * sizeof(float), stream);
    k_pri<<<(V + 255) / 256, 256, 0, stream>>>(features, pri);
    k_build<<<(E + 255) / 256, 256, 0, stream>>>(edges, bm, lenG, lists);
    k_keys<<<(NPAD + 255) / 256, 256, 0, stream>>>(edges, pri, keys);
    k_sort2<<<2, 1024, 0, stream>>>(keys);
    k_mergepath<<<(E / 64 + 63) / 64, 64, 0, stream>>>(keys, edges, pkG);
    k_collapse<<<1, 1024, 0, stream>>>(pkG, lenG, lists, pairsG, mcountG, aliveG, out);
    k_apply<<<V / 256, 256, 0, stream>>>(features, pairsG, mcountG, out);
}

// Round 10
// 9863.608 us; speedup vs baseline: 2.6679x; 2.6679x over previous
//
#include <hip/hip_runtime.h>
#include <stdint.h>

#define V 4096
#define D 128
#define E 12288
#define NPAD 16384
#define HALF 8192
#define TARGET 2048
#define MAXM (V - TARGET)    // 2048 kept merges
#define LCAP 192             // list capacity (u16 entries)
#define MAXW 1536            // winner cap per round
#define ACAP 4096            // total accept cap

// ws layout (bytes)
#define WS_BM     0u                               // V*V bits = 2 MB dedupe bitmap
#define WS_LISTS  (V * (V / 8u))                   // V*LCAP*2 = 1.5 MB
#define WS_LEN    (WS_LISTS + V * LCAP * 2u)       // V u32
#define WS_PRI    (WS_LEN + V * 4u)                // V float
#define WS_KEYS   (WS_PRI + V * 4u)                // NPAD u64
#define WS_PK     (WS_KEYS + NPAD * 8u)            // E u32 (sorted packed edges)
#define WS_PAIRS  (WS_PK + E * 4u)                 // MAXM u32
#define WS_MCOUNT (WS_PAIRS + MAXM * 4u)           // 1 int
#define WS_ALIVE  (WS_MCOUNT + 16u)                // V u8

__device__ __forceinline__ unsigned getf(const uint4& r, int c) {
    unsigned lo = (c & 2) ? r.z : r.x;
    unsigned hi = (c & 2) ? r.w : r.y;
    return (c & 1) ? hi : lo;
}

__device__ __forceinline__ bool inlist(const unsigned short* p, int n, int id) {
    const uint4* pv = (const uint4*)p;
    for (int i0 = 0; i0 < n; i0 += 8) {
        uint4 c = pv[i0 >> 3];
#pragma unroll
        for (int t = 0; t < 4; t++) {
            unsigned wv = getf(c, t);
            int n0 = i0 + 2 * t;
            if (n0 < n && (int)((wv & 0xFFFFu) >> 2) == id) return true;
            if (n0 + 1 < n && (int)(wv >> 18) == id) return true;
        }
    }
    return false;
}

__global__ void k_build(const int* __restrict__ edges, unsigned* __restrict__ bm,
                        unsigned* __restrict__ lenG, unsigned short* __restrict__ lists) {
    int e = blockIdx.x * 256 + threadIdx.x;
    if (e < E) {
        int a = edges[e], b = edges[E + e];
        unsigned o1 = atomicOr(&bm[(a << 7) + (b >> 5)], 1u << (b & 31));
        if (!((o1 >> (b & 31)) & 1u)) {
            unsigned ia = atomicAdd(&lenG[a], 1u);
            if (ia < LCAP) lists[a * LCAP + ia] = (unsigned short)((b << 2) | 2);
        }
        unsigned o2 = atomicOr(&bm[(b << 7) + (a >> 5)], 1u << (a & 31));
        if (!((o2 >> (a & 31)) & 1u)) {
            unsigned ib = atomicAdd(&lenG[b], 1u);
            if (ib < LCAP) lists[b * LCAP + ib] = (unsigned short)((a << 2) | 2);
        }
    }
}

__global__ void k_pri(const float* __restrict__ f, float* __restrict__ pri) {
    int v = blockIdx.x * 256 + threadIdx.x;
    if (v < V) {
        const float* p = f + v * D;
        float r[8];
#pragma unroll
        for (int j = 0; j < 8; j++) r[j] = __fmul_rn(p[j], p[j]);
        for (int i = 8; i < D; i += 8) {
#pragma unroll
            for (int j = 0; j < 8; j++)
                r[j] = __fadd_rn(r[j], __fmul_rn(p[i + j], p[i + j]));
        }
        float s01 = __fadd_rn(r[0], r[1]);
        float s23 = __fadd_rn(r[2], r[3]);
        float s45 = __fadd_rn(r[4], r[5]);
        float s67 = __fadd_rn(r[6], r[7]);
        pri[v] = __fadd_rn(__fadd_rn(s01, s23), __fadd_rn(s45, s67));
    }
}

__global__ void k_keys(const int* __restrict__ edges, const float* __restrict__ pri,
                       unsigned long long* __restrict__ keys) {
    int s = blockIdx.x * 256 + threadIdx.x;
    if (s < NPAD) {
        unsigned long long rec;
        if (s < E) {
            int a = edges[s], b = edges[E + s];
            float k = __fadd_rn(pri[a], pri[b]);
            rec = ((unsigned long long)__float_as_uint(k) << 32) | (unsigned)s;
        } else {
            rec = (0xFFFFFFFFull << 32) | (unsigned)s;
        }
        keys[s] = rec;
    }
}

__launch_bounds__(1024)
__global__ void k_sort2(unsigned long long* __restrict__ keys) {
    __shared__ unsigned long long srt[HALF];
    const int tid = threadIdx.x;
    unsigned long long* base = keys + blockIdx.x * HALF;
    for (int s = tid; s < HALF; s += 1024) srt[s] = base[s];
    __syncthreads();
    for (int k = 2; k <= HALF; k <<= 1) {
        for (int j = k >> 1; j >= 1; j >>= 1) {
            for (int i = tid; i < HALF; i += 1024) {
                int ixj = i ^ j;
                if (ixj > i) {
                    unsigned long long x = srt[i], y = srt[ixj];
                    bool up = ((i & k) == 0);
                    if ((x > y) == up) { srt[i] = y; srt[ixj] = x; }
                }
            }
            __syncthreads();
        }
    }
    for (int s = tid; s < HALF; s += 1024) base[s] = srt[s];
}

__launch_bounds__(64)
__global__ void k_mergepath(const unsigned long long* __restrict__ keys,
                            const int* __restrict__ edges, unsigned* __restrict__ pkG) {
    int t = blockIdx.x * 64 + threadIdx.x;
    if (t >= E / 64) return;
    const unsigned long long* A = keys;
    const unsigned long long* B = keys + HALF;
    int d = t * 64;
    int lo = d > HALF ? d - HALF : 0;
    int hi = d < HALF ? d : HALF;
    while (lo < hi) {
        int mid = (lo + hi) >> 1;
        if (A[mid] < B[d - 1 - mid]) lo = mid + 1; else hi = mid;
    }
    int ia = lo, ib = d - lo;
    for (int o = d; o < d + 64; o++) {
        bool takeA = (ib >= HALF) || (ia < HALF && A[ia] < B[ib]);
        unsigned long long r = takeA ? A[ia++] : B[ib++];
        int e = (int)(r & 0xFFFFFFFFull);
        int a = edges[e], b = edges[E + e];
        pkG[o] = ((unsigned)a << 16) | (unsigned)b;
    }
}

// local-min parallel greedy with EARLY STOP:
// stop once >= MAXM accepts have order < min(undecided order) -- prefix final.
__launch_bounds__(1024, 1)
__global__ void k_collapse(const unsigned* __restrict__ pkG, const unsigned* __restrict__ lenG,
                           unsigned short* lists, unsigned* __restrict__ pairsG,
                           int* __restrict__ mcountG, uint8_t* __restrict__ aliveG,
                           float* __restrict__ out) {
    __shared__ unsigned minE[V];              // 16 KB round-tagged min flagged order
    __shared__ uint8_t  alv[V];               // 4 KB
    __shared__ unsigned short len_[V];        // 8 KB
    __shared__ uint8_t  status[E];            // 12 KB 0=undec 1=rej 2=acc
    __shared__ unsigned short wOrd[MAXW];     // 3 KB
    __shared__ unsigned short rAcc[MAXW];     // 3 KB
    __shared__ unsigned short rL1[MAXW];      // 3 KB
    __shared__ unsigned short accOrd[ACAP];   // 8 KB
    __shared__ int sNW, sNacc, sMinU, sCnt, mcnt;
    const int tid = threadIdx.x;

    unsigned pkR[12];                         // immutable edge list in registers
#pragma unroll
    for (int j = 0; j < 12; j++) pkR[j] = pkG[tid + j * 1024];

    for (int v = tid; v < V; v += 1024) {
        unsigned l = lenG[v];
        len_[v] = (unsigned short)(l > LCAP ? LCAP : l);
        alv[v] = 1; minE[v] = 0xFFFFFFFFu;
    }
    for (int e = tid; e < E; e += 1024) status[e] = 0;
    if (tid == 0) mcnt = 0;
    __syncthreads();

    for (int round = 0; round < 511; round++) {
        const unsigned tagv = (unsigned)(511 - round) << 14;   // decreasing per round
        if (tid == 0) { sNW = 0; sNacc = 0; sMinU = 0x7FFFFFFF; sCnt = 0; }
        __syncthreads();

        // PASS1: predicate eval (monotone reject final); flagged -> tagged minE
#pragma unroll
        for (int j = 0; j < 12; j++) {
            int e = tid + j * 1024;
            if (status[e]) continue;
            unsigned pk = pkR[j];
            int a = (int)(pk >> 16), b = (int)(pk & 0xFFFFu);
            if (!alv[a] || !alv[b]) { status[e] = 1; continue; }
            unsigned val = 0; bool found = false;
            int la = len_[a];
            const uint4* pl = (const uint4*)(lists + (size_t)a * LCAP);
            for (int i0 = 0; i0 < la && !found; i0 += 8) {
                uint4 c = pl[i0 >> 3];
#pragma unroll
                for (int t2 = 0; t2 < 4; t2++) {
                    unsigned wv = getf(c, t2);
                    int n0 = i0 + 2 * t2;
                    if (n0 < la && (int)((wv & 0xFFFFu) >> 2) == b) { val = wv & 3u; found = true; }
                    if (n0 + 1 < la && (int)(wv >> 18) == b) { val = (wv >> 16) & 3u; found = true; }
                }
            }
            if (!found || val != 2u) { status[e] = 1; continue; }
            atomicMin(&minE[a], tagv | (unsigned)e);
            atomicMin(&minE[b], tagv | (unsigned)e);
            atomicMin(&sMinU, e);
        }
        __syncthreads();

        // EARLY STOP: prefix of accepts below minUndec is final
        int minU = sMinU;
        if (minU == 0x7FFFFFFF) break;                      // fully decided
        {
            int mc = mcnt, cntLoc = 0;
            for (int i = tid; i < mc; i += 1024)
                if ((int)accOrd[i] < minU) cntLoc++;
            if (cntLoc) atomicAdd(&sCnt, cntLoc);
            __syncthreads();
            if (sCnt >= MAXM) break;
        }

        // PASS2: winners = tagged min at BOTH endpoints
#pragma unroll
        for (int j = 0; j < 12; j++) {
            int e = tid + j * 1024;
            if (status[e]) continue;
            unsigned pk = pkR[j];
            int a = (int)(pk >> 16), b = (int)(pk & 0xFFFFu);
            unsigned te = tagv | (unsigned)e;
            if (minE[a] == te && minE[b] == te) {
                int t = atomicAdd(&sNW, 1);
                if (t < MAXW) wOrd[t] = (unsigned short)e;
            }
        }
        __syncthreads();
        int nww = sNW < MAXW ? sNW : MAXW;

        // PASS3: adjacency demotion (lower order survives) + accept + rebuild v0
        for (int t = tid; t < nww; t += 1024) {
            int e = wOrd[t];
            unsigned pk = pkG[e];
            int a = (int)(pk >> 16), b = (int)(pk & 0xFFFFu);
            unsigned short* pa = lists + (size_t)a * LCAP;
            unsigned short* pb = lists + (size_t)b * LCAP;
            int la = len_[a], lb = len_[b];
            bool dem = false;
            // v1-side: any lower-order winner endpoint in N(b)
            for (int i = 0; i < lb && !dem; i++) {
                int id = pb[i] >> 2;
                if (id >= V) continue;
                unsigned mv = minE[id];
                if ((mv & ~16383u) != tagv) continue;
                int e2 = (int)(mv & 16383u);
                if (e2 >= e) continue;
                unsigned pk2 = pkG[e2];
                int a2 = (int)(pk2 >> 16), b2 = (int)(pk2 & 0xFFFFu);
                unsigned t2v = tagv | (unsigned)e2;
                if (minE[a2] == t2v && minE[b2] == t2v) dem = true;
            }
            // v0-side: lower-order winner's DYING endpoint in N(a)
            for (int i = 0; i < la && !dem; i++) {
                int id = pa[i] >> 2;
                if (id >= V) continue;
                unsigned mv = minE[id];
                if ((mv & ~16383u) != tagv) continue;
                int e2 = (int)(mv & 16383u);
                if (e2 >= e) continue;
                unsigned pk2 = pkG[e2];
                int a2 = (int)(pk2 >> 16), b2 = (int)(pk2 & 0xFFFFu);
                if (id != b2) continue;                       // must be dying endpoint
                unsigned t2v = tagv | (unsigned)e2;
                if (minE[a2] == t2v && minE[b2] == t2v) dem = true;
            }
            if (dem) continue;                                // retry next round
            // ACCEPT
            status[e] = 2;
            int r = atomicAdd(&sNacc, 1);
            rAcc[r] = (unsigned short)e;
            rL1[r] = (unsigned short)lb;
            int ai = atomicAdd(&mcnt, 1);
            if (ai < ACAP) accOrd[ai] = (unsigned short)e;
            // rebuild v0's list (compact; sole writer)
            int wn = 0;
            for (int i = 0; i < la; i++) {
                unsigned short tv = pa[i];
                int id = tv >> 2;
                if (id >= V || id == b) continue;
                bool inb = inlist(pb, lb, id);
                pa[wn++] = inb ? (unsigned short)((id << 2) | 3u) : tv;
            }
            int wn0 = wn;
            for (int j = 0; j < lb; j++) {
                unsigned short uv = pb[j];
                int id = uv >> 2;
                if (id >= V || id == a) continue;
                if (!inlist(pa, wn0, id) && wn < LCAP) pa[wn++] = uv;
            }
            len_[a] = (unsigned short)wn;
            len_[b] = 0;
            alv[b] = 0;
        }
        __syncthreads();

        // PASS4: fix lists of x in N(v1), 8 threads per accept
        int na = sNacc;
        for (int s = tid; s < na * 8; s += 1024) {
            int t = s >> 3, j0 = s & 7;
            int e = rAcc[t];
            unsigned pk = pkG[e];
            int a = (int)(pk >> 16), b = (int)(pk & 0xFFFFu);
            int l1 = rL1[t];
            const unsigned short* pb = lists + (size_t)b * LCAP;
            for (int j = j0; j < l1; j += 8) {
                unsigned short uv = pb[j];
                int x = uv >> 2;
                if (x >= V || x == a) continue;
                unsigned short* px = lists + (size_t)x * LCAP;
                int lx = len_[x];
                int pV1 = -1, pV0 = -1;
                const uint4* pv = (const uint4*)px;
                for (int i0 = 0; i0 < lx; i0 += 8) {
                    uint4 c = pv[i0 >> 3];
#pragma unroll
                    for (int t2 = 0; t2 < 4; t2++) {
                        unsigned wv = getf(c, t2);
                        int n0 = i0 + 2 * t2;
                        int id0 = (int)((wv & 0xFFFFu) >> 2), id1 = (int)(wv >> 18);
                        if (n0 < lx) { if (id0 == b) pV1 = n0; else if (id0 == a) pV0 = n0; }
                        if (n0 + 1 < lx) { if (id1 == b) pV1 = n0 + 1; else if (id1 == a) pV0 = n0 + 1; }
                    }
                }
                if (pV1 < 0) continue;
                if (pV0 >= 0) {                     // adj both: clamp a-entry, hole b-entry
                    px[pV0] = (unsigned short)((a << 2) | 3u);
                    px[pV1] = 0xFFFF;
                } else {                            // rewrite b-entry -> (a, val)
                    px[pV1] = (unsigned short)((a << 2) | (uv & 3u));
                }
            }
        }
        __syncthreads();
    }

    // FINAL: sort accepts by order; keep first MAXM; rebuild alive
    int M = mcnt; if (M > ACAP) M = ACAP;
    for (int i = tid; i < ACAP; i += 1024) if (i >= M) accOrd[i] = 0xFFFF;
    __syncthreads();
    for (int k = 2; k <= ACAP; k <<= 1) {
        for (int j = k >> 1; j >= 1; j >>= 1) {
            for (int i = tid; i < ACAP; i += 1024) {
                int ix = i ^ j;
                if (ix > i) {
                    unsigned short x = accOrd[i], y = accOrd[ix];
                    bool up = ((i & k) == 0);
                    if ((x > y) == up) { accOrd[i] = y; accOrd[ix] = x; }
                }
            }
            __syncthreads();
        }
    }
    int K = M < MAXM ? M : MAXM;
    for (int v = tid; v < V; v += 1024) alv[v] = 1;
    __syncthreads();
    for (int i = tid; i < K; i += 1024) {
        int e = accOrd[i];
        unsigned pk = pkG[e];
        pairsG[i] = pk;
        alv[pk & 0xFFFFu] = 0;
    }
    __syncthreads();
    for (int v = tid; v < V; v += 1024) {
        aliveG[v] = alv[v];
        out[V * D + v] = alv[v] ? 1.0f : 0.0f;
    }
    if (tid == 0) { mcountG[0] = K; out[V * D + V] = (float)(V - K); }
}

__launch_bounds__(256)
__global__ void k_apply(const float* __restrict__ f, const unsigned* __restrict__ pairsG,
                        const int* __restrict__ mcountG, float* __restrict__ out) {
    __shared__ unsigned pl[MAXM];
    __shared__ int rootL[256];
    __shared__ float wL[256];
    const int tid = threadIdx.x;
    const int mc = mcountG[0];
    for (int j = tid; j < mc; j += 256) pl[j] = pairsG[j];
    __syncthreads();
    int cur = blockIdx.x * 256 + tid;
    float w = 1.0f;
    for (int j = 0; j < mc; j++) {
        unsigned p = pl[j];
        int v0 = (int)(p >> 16), v1 = (int)(p & 0xFFFFu);
        if (cur == v1) { cur = v0; w *= 0.5f; }
        else if (cur == v0) w *= 0.5f;
    }
    rootL[tid] = cur;
    wL[tid] = w;
    __syncthreads();
    const int sub = tid >> 7;
    const int d = tid & 127;
    for (int s = 0; s < 256; s += 2) {
        int idx = s + sub;
        int vv = blockIdx.x * 256 + idx;
        atomicAdd(&out[rootL[idx] * D + d], wL[idx] * f[vv * D + d]);
    }
}

extern "C" void kernel_launch(void* const* d_in, const int* in_sizes, int n_in,
                              void* d_out, int out_size, void* d_ws, size_t ws_size,
                              hipStream_t stream) {
    (void)in_sizes; (void)n_in; (void)out_size; (void)ws_size;
    const float* features = (const float*)d_in[0];
    const int* edges = (const int*)d_in[1];
    uint8_t* ws = (uint8_t*)d_ws;
    unsigned* bm = (unsigned*)(ws + WS_BM);
    unsigned short* lists = (unsigned short*)(ws + WS_LISTS);
    unsigned* lenG = (unsigned*)(ws + WS_LEN);
    float* pri = (float*)(ws + WS_PRI);
    unsigned long long* keys = (unsigned long long*)(ws + WS_KEYS);
    unsigned* pkG = (unsigned*)(ws + WS_PK);
    unsigned* pairsG = (unsigned*)(ws + WS_PAIRS);
    int* mcountG = (int*)(ws + WS_MCOUNT);
    uint8_t* aliveG = ws + WS_ALIVE;
    float* out = (float*)d_out;

    hipMemsetAsync(bm, 0, (size_t)V * (V / 8), stream);
    hipMemsetAsync(lenG, 0, (size_t)V * 4, stream);
    hipMemsetAsync(out, 0, (size_t)V * D * sizeof(float), stream);
    k_pri<<<(V + 255) / 256, 256, 0, stream>>>(features, pri);
    k_build<<<(E + 255) / 256, 256, 0, stream>>>(edges, bm, lenG, lists);
    k_keys<<<(NPAD + 255) / 256, 256, 0, stream>>>(edges, pri, keys);
    k_sort2<<<2, 1024, 0, stream>>>(keys);
    k_mergepath<<<(E / 64 + 63) / 64, 64, 0, stream>>>(keys, edges, pkG);
    k_collapse<<<1, 1024, 0, stream>>>(pkG, lenG, lists, pairsG, mcountG, aliveG, out);
    k_apply<<<V / 256, 256, 0, stream>>>(features, pairsG, mcountG, out);
}